// Round 1
// 647.096 us; speedup vs baseline: 1.0212x; 1.0212x over previous
//
#include <hip/hip_runtime.h>
#include <math.h>

#define MAX_T 128

typedef float f4 __attribute__((ext_vector_type(4)));

__global__ __launch_bounds__(256) void sde_kernel(
    const float* __restrict__ y0,
    const float* __restrict__ ts,
    const float* __restrict__ noise,
    const float* __restrict__ theta_p,
    float* __restrict__ out,
    int n4, int T)
{
    // Per-step uniform constants, packed so each step is ONE ds_read_b128:
    //   c.x = 1 + theta*dt      (y multiplier)
    //   c.y = sin(t) * dt       (additive drift)
    //   c.z = cos(t)            (sigmoid argument scale)
    //   c.w = 0.3 * sqrt(dt)    (diffusion scale)
    __shared__ f4 s_c[MAX_T];
    int tid = threadIdx.x;
    float theta = theta_p[0];
    if (tid < T - 1) {
        float t  = ts[tid];
        float dt = ts[tid + 1] - t;
        f4 c;
        c.x = 1.0f + theta * dt;
        c.y = sinf(t) * dt;
        c.z = cosf(t);
        c.w = 0.3f * sqrtf(dt);
        s_c[tid] = c;
    }
    __syncthreads();

    int idx = blockIdx.x * blockDim.x + threadIdx.x;
    if (idx >= n4) return;

    const f4* __restrict__ y0v = (const f4*)y0;
    const f4* __restrict__ nv  = (const f4*)noise;
    f4* __restrict__       outv = (f4*)out;

    f4 y = y0v[idx];
    __builtin_nontemporal_store(y, &outv[idx]);   // out[0] = y0

    const int NT = T - 1;

    // Prefetch depth 4: four independent noise loads in flight per thread
    // (64 B/lane, 4 KB/wave, ~64 KB/CU at 16 waves/CU). Manual 4-unroll with
    // named registers z0..z3 -> no register rotation moves, no runtime array
    // indexing (stays in VGPRs, no scratch).
    f4 zinit = {0.f, 0.f, 0.f, 0.f};
    f4 z0 = zinit, z1 = zinit, z2 = zinit, z3 = zinit;
    if (0 < NT) z0 = __builtin_nontemporal_load(&nv[idx]);
    if (1 < NT) z1 = __builtin_nontemporal_load(&nv[(size_t)n4 + idx]);
    if (2 < NT) z2 = __builtin_nontemporal_load(&nv[(size_t)2 * n4 + idx]);
    if (3 < NT) z3 = __builtin_nontemporal_load(&nv[(size_t)3 * n4 + idx]);

    // y' = fma(d*sig, z, fma(y, a, b)); sig = 1/(1+exp(-(c * exp(-y))))
    #define ELEM(comp) { \
        float e   = __expf(-y.comp); \
        float sig = __builtin_amdgcn_rcpf(1.0f + __expf(-(c.z * e))); \
        y.comp = fmaf(c.w * sig, zz.comp, fmaf(y.comp, c.x, c.y)); }

    #define BODY(Z, tt) { \
        if ((tt) < NT) { \
            f4 c  = s_c[(tt)]; \
            f4 zz = Z; \
            if ((tt) + 4 < NT) \
                Z = __builtin_nontemporal_load(&nv[(size_t)((tt) + 4) * n4 + idx]); \
            ELEM(x); ELEM(y); ELEM(z); ELEM(w); \
            __builtin_nontemporal_store(y, &outv[(size_t)((tt) + 1) * n4 + idx]); \
        } }

    for (int t = 0; t < NT; t += 4) {
        BODY(z0, t);
        BODY(z1, t + 1);
        BODY(z2, t + 2);
        BODY(z3, t + 3);
    }

    #undef BODY
    #undef ELEM
}

extern "C" void kernel_launch(void* const* d_in, const int* in_sizes, int n_in,
                              void* d_out, int out_size, void* d_ws, size_t ws_size,
                              hipStream_t stream) {
    const float* y0    = (const float*)d_in[0];
    const float* ts    = (const float*)d_in[1];
    const float* noise = (const float*)d_in[2];
    const float* theta = (const float*)d_in[3];
    float* out = (float*)d_out;

    int n = in_sizes[0];      // B*D
    int T = in_sizes[1];      // number of timesteps
    int n4 = n / 4;           // float4 granularity (B*D divisible by 4)

    int block = 256;
    int grid = (n4 + block - 1) / block;
    sde_kernel<<<grid, block, 0, stream>>>(y0, ts, noise, theta, out, n4, T);
}